// Round 2
// baseline (1225.112 us; speedup 1.0000x reference)
//
#include <hip/hip_runtime.h>
#include <hip/hip_fp16.h>
#include <type_traits>
#include <math.h>

// Problem constants
constexpr int N    = 50000;
constexpr int E    = 1600000;
constexpr int F    = 256;        // HEADS*HID
constexpr int EL   = E + N;      // edges + self loops
constexpr int NBLK = (N + 255) / 256;  // 196 scan blocks
#define TM 8

// ---- storage-type conversion helpers --------------------------------------
template <typename T> __device__ inline T toT(float v);
template <> __device__ inline float  toT<float>(float v)  { return v; }
template <> __device__ inline __half toT<__half>(float v) { return __float2half_rn(v); }
__device__ inline float toFloat(float v)  { return v; }
__device__ inline float toFloat(__half v) { return __half2float(v); }

// ---------------------------------------------------------------------------
// Kernel 1: xp = x @ W  (fp32 math, LDS-staged, 8 nodes/block for W reuse)
// also a_src[n,h] = sum_c xp[n,h,c]*att_src[h,c] (same for a_dst), in fp32.
// Thread t owns output column t = h*64+c; wave w == head w.
// ---------------------------------------------------------------------------
template <typename TX>
__global__ __launch_bounds__(256) void k_xw(
    const float* __restrict__ x, const float* __restrict__ W,
    const float* __restrict__ att_src, const float* __restrict__ att_dst,
    TX* __restrict__ xp, float* __restrict__ a_src, float* __restrict__ a_dst) {
  __shared__ float xs[TM][F];
  const int t  = threadIdx.x;
  const int n0 = blockIdx.x * TM;
  #pragma unroll
  for (int m = 0; m < TM; ++m) xs[m][t] = x[(size_t)(n0 + m) * F + t];
  __syncthreads();

  float acc[TM];
  #pragma unroll
  for (int m = 0; m < TM; ++m) acc[m] = 0.f;

  for (int k = 0; k < F; ++k) {
    const float wv = W[k * F + t];
    #pragma unroll
    for (int m = 0; m < TM; ++m) acc[m] += xs[m][k] * wv;
  }

  const int hd = t >> 6, lane = t & 63;
  const float asw = att_src[t];
  const float adw = att_dst[t];
  #pragma unroll
  for (int m = 0; m < TM; ++m) {
    const float v = acc[m];
    xp[(size_t)(n0 + m) * F + t] = toT<TX>(v);
    float ps = v * asw, pd = v * adw;
    #pragma unroll
    for (int off = 32; off; off >>= 1) {
      ps += __shfl_down(ps, off, 64);
      pd += __shfl_down(pd, off, 64);
    }
    if (lane == 0) {
      a_src[(n0 + m) * 4 + hd] = ps;
      a_dst[(n0 + m) * 4 + hd] = pd;
    }
  }
}

// ---------------------------------------------------------------------------
// CSR construction: histogram -> 3-phase exclusive scan -> atomic scatter
// ---------------------------------------------------------------------------
__global__ void k_hist(const int* __restrict__ ei, int* __restrict__ counts) {
  const int i = blockIdx.x * blockDim.x + threadIdx.x;
  if (i < E) atomicAdd(&counts[ei[E + i]], 1);   // ei[E+i] = dst
}

__global__ __launch_bounds__(256) void k_scan1(
    const int* __restrict__ counts, int* __restrict__ offsets, int* __restrict__ partials) {
  __shared__ int s[256];
  const int t = threadIdx.x;
  const int i = blockIdx.x * 256 + t;
  const int v = (i < N) ? counts[i] + 1 : 0;     // +1 = self loop
  s[t] = v;
  __syncthreads();
  for (int off = 1; off < 256; off <<= 1) {
    const int add = (t >= off) ? s[t - off] : 0;
    __syncthreads();
    s[t] += add;
    __syncthreads();
  }
  if (i < N) offsets[i] = s[t] - v;              // local exclusive
  if (t == 255) partials[blockIdx.x] = s[255];   // block total
}

__global__ __launch_bounds__(256) void k_scan2(int* __restrict__ partials) {
  __shared__ int s[256];
  const int t = threadIdx.x;
  const int v = (t < NBLK) ? partials[t] : 0;
  s[t] = v;
  __syncthreads();
  for (int off = 1; off < 256; off <<= 1) {
    const int add = (t >= off) ? s[t - off] : 0;
    __syncthreads();
    s[t] += add;
    __syncthreads();
  }
  if (t < NBLK) partials[t] = s[t] - v;          // exclusive block offsets
}

__global__ void k_scan3(int* __restrict__ offsets, const int* __restrict__ partials,
                        int* __restrict__ cursor) {
  const int i = blockIdx.x * 256 + threadIdx.x;
  if (i < N) {
    const int v = offsets[i] + partials[blockIdx.x];
    offsets[i] = v;
    cursor[i]  = v;
  }
  if (i == 0) offsets[N] = EL;
}

__global__ void k_scatter(const int* __restrict__ ei, int* __restrict__ cursor,
                          int* __restrict__ srcs) {
  const int i = blockIdx.x * blockDim.x + threadIdx.x;
  if (i >= EL) return;
  int s, d;
  if (i < E) { s = ei[i]; d = ei[E + i]; }
  else       { s = d = i - E; }                  // self loop
  const int pos = atomicAdd(&cursor[d], 1);
  srcs[pos] = s;
}

// ---------------------------------------------------------------------------
// Segment softmax + weighted aggregation + bias + leaky. One block per node.
// ---------------------------------------------------------------------------
template <typename TX, typename TH>
__global__ __launch_bounds__(256) void k_agg(
    const TX* __restrict__ xp, const float* __restrict__ a_src,
    const float* __restrict__ a_dst, const int* __restrict__ srcs,
    const int* __restrict__ offsets, const float* __restrict__ bias,
    TH* __restrict__ hout) {
  const int n = blockIdx.x;
  const int t = threadIdx.x, hd = t >> 6, lane = t & 63;
  const int beg = offsets[n], end = offsets[n + 1];
  const float adst = a_dst[n * 4 + hd];

  float m = -1e30f;
  for (int i = beg + lane; i < end; i += 64) {
    const int s = srcs[i];
    float al = a_src[s * 4 + hd] + adst;
    al = al > 0.f ? al : 0.2f * al;
    m = fmaxf(m, al);
  }
  #pragma unroll
  for (int off = 1; off < 64; off <<= 1) m = fmaxf(m, __shfl_xor(m, off, 64));

  float acc = 0.f, den = 0.f;
  for (int i = beg; i < end; ++i) {
    const int s = srcs[i];
    float al = a_src[s * 4 + hd] + adst;
    al = al > 0.f ? al : 0.2f * al;
    const float w = __expf(al - m);
    den += w;
    acc += w * toFloat(xp[(size_t)s * F + t]);
  }
  float o = acc / (den + 1e-16f) + bias[t];
  o = o > 0.f ? o : 0.01f * o;
  hout[(size_t)n * F + t] = toT<TH>(o);
}

// ---------------------------------------------------------------------------
// Edge scoring. One wave per edge (4 edges / block). Lane owns 4 features.
// ---------------------------------------------------------------------------
template <typename TH>
__global__ __launch_bounds__(256) void k_score(
    const TH* __restrict__ h, const int* __restrict__ ei,
    const float* __restrict__ fc1W, const float* __restrict__ fc1b,
    float* __restrict__ out) {
  const int e = blockIdx.x * 4 + (threadIdx.x >> 6);
  const int lane = threadIdx.x & 63;
  if (e >= E) return;
  const int s = ei[e], d = ei[E + e];

  float hs0, hs1, hs2, hs3, hd0, hd1, hd2, hd3;
  if constexpr (std::is_same<TH, float>::value) {
    const float4 a = *(const float4*)(h + (size_t)s * F + lane * 4);
    const float4 b = *(const float4*)(h + (size_t)d * F + lane * 4);
    hs0 = a.x; hs1 = a.y; hs2 = a.z; hs3 = a.w;
    hd0 = b.x; hd1 = b.y; hd2 = b.z; hd3 = b.w;
  } else {
    const __half2* pa = (const __half2*)(h + (size_t)s * F + lane * 4);
    const __half2* pb = (const __half2*)(h + (size_t)d * F + lane * 4);
    const __half2 a0 = pa[0], a1 = pa[1], b0 = pb[0], b1 = pb[1];
    hs0 = __low2float(a0); hs1 = __high2float(a0);
    hs2 = __low2float(a1); hs3 = __high2float(a1);
    hd0 = __low2float(b0); hd1 = __high2float(b0);
    hd2 = __low2float(b1); hd3 = __high2float(b1);
  }
  const float r0 = hs0 * hd0 * 0.5f;
  const float r1 = hs1 * hd1 * 0.5f;
  const float r2 = hs2 * hd2 * 0.5f;
  const float r3 = hs3 * hd3 * 0.5f;

  const float4* wp = (const float4*)(fc1W + lane * 12);
  const float4 wa = wp[0], wb = wp[1], wc = wp[2];
  float p0 = r0 * wa.x + r1 * wa.w + r2 * wb.z + r3 * wc.y;
  float p1 = r0 * wa.y + r1 * wb.x + r2 * wb.w + r3 * wc.z;
  float p2 = r0 * wa.z + r1 * wb.y + r2 * wc.x + r3 * wc.w;

  #pragma unroll
  for (int off = 1; off < 64; off <<= 1) {
    p0 += __shfl_xor(p0, off, 64);
    p1 += __shfl_xor(p1, off, 64);
    p2 += __shfl_xor(p2, off, 64);
  }
  if (lane == 0) {
    out[(size_t)e * 3 + 0] = p0 + fc1b[0];
    out[(size_t)e * 3 + 1] = p1 + fc1b[1];
    out[(size_t)e * 3 + 2] = p2 + fc1b[2];
  }
}

// ---------------------------------------------------------------------------
static inline size_t align256(size_t b) { return (b + 255) & ~(size_t)255; }

static inline size_t layout_bytes(size_t sx, size_t sh) {
  size_t tot = 0;
  tot += align256((size_t)N * F * sx);        // xp
  tot += align256((size_t)N * F * sh);        // hbuf
  tot += align256((size_t)N * 4 * 4);         // a_src
  tot += align256((size_t)N * 4 * 4);         // a_dst
  tot += align256((size_t)N * 4);             // counts
  tot += align256((size_t)(N + 1) * 4);       // offsets
  tot += align256(256 * 4);                   // partial
  tot += align256((size_t)N * 4);             // cursor
  tot += align256((size_t)EL * 4);            // srcs
  return tot;
}

template <typename TX, typename TH>
static void run_path(const float* x, const int* ei, const float* W,
                     const float* attS, const float* attD, const float* bias,
                     const float* fc1W, const float* fc1b, float* out,
                     char* ws, hipStream_t stream) {
  size_t off = 0;
  auto alloc = [&](size_t bytes) -> void* {
    void* p = ws + off;
    off += align256(bytes);
    return p;
  };
  TX*    xp      = (TX*)   alloc((size_t)N * F * sizeof(TX));
  TH*    hbuf    = (TH*)   alloc((size_t)N * F * sizeof(TH));
  float* a_src   = (float*)alloc((size_t)N * 4 * sizeof(float));
  float* a_dst   = (float*)alloc((size_t)N * 4 * sizeof(float));
  int*   counts  = (int*)  alloc((size_t)N * sizeof(int));
  int*   offsets = (int*)  alloc((size_t)(N + 1) * sizeof(int));
  int*   partial = (int*)  alloc(256 * sizeof(int));
  int*   cursor  = (int*)  alloc((size_t)N * sizeof(int));
  int*   srcs    = (int*)  alloc((size_t)EL * sizeof(int));

  hipMemsetAsync(counts, 0, (size_t)N * sizeof(int), stream);

  k_xw<TX><<<N / TM, 256, 0, stream>>>(x, W, attS, attD, xp, a_src, a_dst);
  k_hist<<<(E + 255) / 256, 256, 0, stream>>>(ei, counts);
  k_scan1<<<NBLK, 256, 0, stream>>>(counts, offsets, partial);
  k_scan2<<<1, 256, 0, stream>>>(partial);
  k_scan3<<<NBLK, 256, 0, stream>>>(offsets, partial, cursor);
  k_scatter<<<(EL + 255) / 256, 256, 0, stream>>>(ei, cursor, srcs);
  k_agg<TX, TH><<<N, 256, 0, stream>>>(xp, a_src, a_dst, srcs, offsets, bias, hbuf);
  k_score<TH><<<(E + 3) / 4, 256, 0, stream>>>(hbuf, ei, fc1W, fc1b, out);
}

extern "C" void kernel_launch(void* const* d_in, const int* in_sizes, int n_in,
                              void* d_out, int out_size, void* d_ws, size_t ws_size,
                              hipStream_t stream) {
  const float* x    = (const float*)d_in[0];
  const int*   ei   = (const int*)  d_in[1];   // [2,E] flat: [0:E]=src, [E:2E]=dst
  const float* W    = (const float*)d_in[2];
  const float* attS = (const float*)d_in[3];
  const float* attD = (const float*)d_in[4];
  const float* bias = (const float*)d_in[5];
  const float* fc1W = (const float*)d_in[6];
  const float* fc1b = (const float*)d_in[7];
  float*       out  = (float*)d_out;
  char*        ws   = (char*)d_ws;

  // Deterministic tier choice (ws_size constant across calls -> same work
  // every call). fp32 scratch needs ~111.2 MB; fp16 scratch ~60.2 MB.
  if (ws_size >= layout_bytes(sizeof(float), sizeof(float))) {
    run_path<float, float>(x, ei, W, attS, attD, bias, fc1W, fc1b, out, ws, stream);
  } else {
    run_path<__half, __half>(x, ei, W, attS, attD, bias, fc1W, fc1b, out, ws, stream);
  }
}

// Round 3
// 967.060 us; speedup vs baseline: 1.2668x; 1.2668x over previous
//
#include <hip/hip_runtime.h>
#include <hip/hip_fp16.h>
#include <math.h>

// Problem constants
constexpr int N    = 50000;
constexpr int E    = 1600000;
constexpr int F    = 256;        // HEADS*HID
constexpr int EL   = E + N;      // edges + self loops
constexpr int NBLK = (N + 255) / 256;  // 196 scan blocks
#define TM 8

// ---------------------------------------------------------------------------
// Kernel 1: xp = x @ W  (fp32 math, LDS-staged, 8 nodes/block for W reuse)
// xp stored fp16 (gather-bandwidth optimization); a_src/a_dst fp32 from the
// fp32 accumulator so attention logits are exact.
// Thread t owns output column t = h*64+c; wave w == head w.
// ---------------------------------------------------------------------------
__global__ __launch_bounds__(256) void k_xw(
    const float* __restrict__ x, const float* __restrict__ W,
    const float* __restrict__ att_src, const float* __restrict__ att_dst,
    __half* __restrict__ xp, float* __restrict__ a_src, float* __restrict__ a_dst) {
  __shared__ float xs[TM][F];
  const int t  = threadIdx.x;
  const int n0 = blockIdx.x * TM;
  #pragma unroll
  for (int m = 0; m < TM; ++m) xs[m][t] = x[(size_t)(n0 + m) * F + t];
  __syncthreads();

  float acc[TM];
  #pragma unroll
  for (int m = 0; m < TM; ++m) acc[m] = 0.f;

  for (int k = 0; k < F; ++k) {
    const float wv = W[k * F + t];          // uniform-address xs broadcast, no conflict
    #pragma unroll
    for (int m = 0; m < TM; ++m) acc[m] += xs[m][k] * wv;
  }

  const int hd = t >> 6, lane = t & 63;
  const float asw = att_src[t];
  const float adw = att_dst[t];
  #pragma unroll
  for (int m = 0; m < TM; ++m) {
    const float v = acc[m];
    xp[(size_t)(n0 + m) * F + t] = __float2half_rn(v);
    float ps = v * asw, pd = v * adw;
    #pragma unroll
    for (int off = 32; off; off >>= 1) {
      ps += __shfl_down(ps, off, 64);
      pd += __shfl_down(pd, off, 64);
    }
    if (lane == 0) {
      a_src[(n0 + m) * 4 + hd] = ps;
      a_dst[(n0 + m) * 4 + hd] = pd;
    }
  }
}

// ---------------------------------------------------------------------------
// CSR construction: histogram -> 3-phase exclusive scan -> atomic scatter
// ---------------------------------------------------------------------------
__global__ void k_hist(const int* __restrict__ ei, int* __restrict__ counts) {
  const int i = blockIdx.x * blockDim.x + threadIdx.x;
  if (i < E) atomicAdd(&counts[ei[E + i]], 1);   // ei[E+i] = dst
}

__global__ __launch_bounds__(256) void k_scan1(
    const int* __restrict__ counts, int* __restrict__ offsets, int* __restrict__ partials) {
  __shared__ int s[256];
  const int t = threadIdx.x;
  const int i = blockIdx.x * 256 + t;
  const int v = (i < N) ? counts[i] + 1 : 0;     // +1 = self loop
  s[t] = v;
  __syncthreads();
  for (int off = 1; off < 256; off <<= 1) {
    const int add = (t >= off) ? s[t - off] : 0;
    __syncthreads();
    s[t] += add;
    __syncthreads();
  }
  if (i < N) offsets[i] = s[t] - v;              // local exclusive
  if (t == 255) partials[blockIdx.x] = s[255];   // block total
}

__global__ __launch_bounds__(256) void k_scan2(int* __restrict__ partials) {
  __shared__ int s[256];
  const int t = threadIdx.x;
  const int v = (t < NBLK) ? partials[t] : 0;
  s[t] = v;
  __syncthreads();
  for (int off = 1; off < 256; off <<= 1) {
    const int add = (t >= off) ? s[t - off] : 0;
    __syncthreads();
    s[t] += add;
    __syncthreads();
  }
  if (t < NBLK) partials[t] = s[t] - v;          // exclusive block offsets
}

__global__ void k_scan3(int* __restrict__ offsets, const int* __restrict__ partials,
                        int* __restrict__ cursor) {
  const int i = blockIdx.x * 256 + threadIdx.x;
  if (i < N) {
    const int v = offsets[i] + partials[blockIdx.x];
    offsets[i] = v;
    cursor[i]  = v;
  }
  if (i == 0) offsets[N] = EL;
}

__global__ void k_scatter(const int* __restrict__ ei, int* __restrict__ cursor,
                          int* __restrict__ srcs, int* __restrict__ eids) {
  const int i = blockIdx.x * blockDim.x + threadIdx.x;
  if (i >= EL) return;
  int s, d, id;
  if (i < E) { s = ei[i]; d = ei[E + i]; id = i; }
  else       { s = d = i - E; id = -1; }          // self loop: no score output
  const int pos = atomicAdd(&cursor[d], 1);
  srcs[pos] = s;
  eids[pos] = id;
}

// ---------------------------------------------------------------------------
// Segment softmax + aggregation + bias + leaky. One block (128 thr) per node.
// Thread t owns features {2t, 2t+1} (one __half2 gather / thread);
// head = t>>5, so per-head reductions are 32-lane butterflies.
// ---------------------------------------------------------------------------
__global__ __launch_bounds__(128) void k_agg(
    const __half2* __restrict__ xp2, const float* __restrict__ a_src,
    const float* __restrict__ a_dst, const int* __restrict__ srcs,
    const int* __restrict__ offsets, const float* __restrict__ bias,
    __half2* __restrict__ h2) {
  const int n = blockIdx.x;
  const int t = threadIdx.x;              // 0..127
  const int hd = t >> 5;
  const int beg = offsets[n], end = offsets[n + 1];
  const float adst = a_dst[n * 4 + hd];

  float m = -1e30f;
  for (int i = beg + (t & 31); i < end; i += 32) {
    float al = a_src[srcs[i] * 4 + hd] + adst;
    al = al > 0.f ? al : 0.2f * al;
    m = fmaxf(m, al);
  }
  #pragma unroll
  for (int off = 16; off >= 1; off >>= 1) m = fmaxf(m, __shfl_xor(m, off, 64));

  float acc0 = 0.f, acc1 = 0.f, den = 0.f;
  int s_next = srcs[beg];
  for (int i = beg; i < end; ++i) {
    const int s = s_next;
    if (i + 1 < end) s_next = srcs[i + 1];
    const __half2 v = xp2[(size_t)s * 128 + t];   // issue gather early
    float al = a_src[s * 4 + hd] + adst;
    al = al > 0.f ? al : 0.2f * al;
    const float w = __expf(al - m);
    den += w;
    acc0 += w * __low2float(v);
    acc1 += w * __high2float(v);
  }
  const float inv = 1.f / (den + 1e-16f);
  float o0 = acc0 * inv + bias[2 * t];
  float o1 = acc1 * inv + bias[2 * t + 1];
  o0 = o0 > 0.f ? o0 : 0.01f * o0;
  o1 = o1 > 0.f ? o1 : 0.01f * o1;
  h2[(size_t)n * 128 + t] = __floats2half2_rn(o0, o1);
}

// ---------------------------------------------------------------------------
// Edge scoring, dst-grouped: one wave per dst node; h[dst] stays in registers,
// only h[src] gathered per edge (halves gather traffic vs edge-parallel).
// Lane owns 4 features (one 8B fp16 load). eid<0 = self loop, skipped
// (wave-uniform branch).
// ---------------------------------------------------------------------------
__global__ __launch_bounds__(256) void k_score(
    const __half2* __restrict__ h2, const int* __restrict__ srcs,
    const int* __restrict__ eids, const int* __restrict__ offsets,
    const float* __restrict__ fc1W, const float* __restrict__ fc1b,
    float* __restrict__ out) {
  const int n = blockIdx.x * 4 + (threadIdx.x >> 6);
  const int lane = threadIdx.x & 63;
  if (n >= N) return;

  const float4* wp = (const float4*)(fc1W + lane * 12);
  const float4 wa = wp[0], wb = wp[1], wc = wp[2];
  const float b0 = fc1b[0], b1 = fc1b[1], b2 = fc1b[2];

  const uint2 draw = *(const uint2*)(h2 + (size_t)n * 128 + lane * 2);
  const __half2 dl = *(const __half2*)&draw.x;
  const __half2 dh = *(const __half2*)&draw.y;
  const float hd0 = __low2float(dl) * 0.5f, hd1 = __high2float(dl) * 0.5f;
  const float hd2 = __low2float(dh) * 0.5f, hd3 = __high2float(dh) * 0.5f;

  const int beg = offsets[n], end = offsets[n + 1];
  for (int i = beg; i < end; ++i) {
    const int eid = eids[i];
    if (eid < 0) continue;                 // self loop
    const int s = srcs[i];
    const uint2 sraw = *(const uint2*)(h2 + (size_t)s * 128 + lane * 2);
    const __half2 sl = *(const __half2*)&sraw.x;
    const __half2 sh = *(const __half2*)&sraw.y;
    const float r0 = __low2float(sl)  * hd0;
    const float r1 = __high2float(sl) * hd1;
    const float r2 = __low2float(sh)  * hd2;
    const float r3 = __high2float(sh) * hd3;

    float p0 = r0 * wa.x + r1 * wa.w + r2 * wb.z + r3 * wc.y;
    float p1 = r0 * wa.y + r1 * wb.x + r2 * wb.w + r3 * wc.z;
    float p2 = r0 * wa.z + r1 * wb.y + r2 * wc.x + r3 * wc.w;

    #pragma unroll
    for (int off = 1; off < 64; off <<= 1) {
      p0 += __shfl_xor(p0, off, 64);
      p1 += __shfl_xor(p1, off, 64);
      p2 += __shfl_xor(p2, off, 64);
    }
    if (lane == 0) {
      out[(size_t)eid * 3 + 0] = p0 + b0;
      out[(size_t)eid * 3 + 1] = p1 + b1;
      out[(size_t)eid * 3 + 2] = p2 + b2;
    }
  }
}

// ---------------------------------------------------------------------------
static inline size_t align256(size_t b) { return (b + 255) & ~(size_t)255; }

extern "C" void kernel_launch(void* const* d_in, const int* in_sizes, int n_in,
                              void* d_out, int out_size, void* d_ws, size_t ws_size,
                              hipStream_t stream) {
  const float* x    = (const float*)d_in[0];
  const int*   ei   = (const int*)  d_in[1];   // [2,E] flat: [0:E]=src, [E:2E]=dst
  const float* W    = (const float*)d_in[2];
  const float* attS = (const float*)d_in[3];
  const float* attD = (const float*)d_in[4];
  const float* bias = (const float*)d_in[5];
  const float* fc1W = (const float*)d_in[6];
  const float* fc1b = (const float*)d_in[7];
  float*       out  = (float*)d_out;
  char*        ws   = (char*)d_ws;

  size_t off = 0;
  auto alloc = [&](size_t bytes) -> void* {
    void* p = ws + off;
    off += align256(bytes);
    return p;
  };
  __half* xp      = (__half*)alloc((size_t)N * F * sizeof(__half));  // 25.6 MB
  __half* hbuf    = (__half*)alloc((size_t)N * F * sizeof(__half));  // 25.6 MB
  float*  a_src   = (float*) alloc((size_t)N * 4 * sizeof(float));
  float*  a_dst   = (float*) alloc((size_t)N * 4 * sizeof(float));
  int*    counts  = (int*)   alloc((size_t)N * sizeof(int));
  int*    offsets = (int*)   alloc((size_t)(N + 1) * sizeof(int));
  int*    partial = (int*)   alloc(256 * sizeof(int));
  int*    cursor  = (int*)   alloc((size_t)N * sizeof(int));
  int*    srcs    = (int*)   alloc((size_t)EL * sizeof(int));        // 6.6 MB
  int*    eids    = (int*)   alloc((size_t)EL * sizeof(int));        // 6.6 MB

  hipMemsetAsync(counts, 0, (size_t)N * sizeof(int), stream);

  k_xw<<<N / TM, 256, 0, stream>>>(x, W, attS, attD, xp, a_src, a_dst);
  k_hist<<<(E + 255) / 256, 256, 0, stream>>>(ei, counts);
  k_scan1<<<NBLK, 256, 0, stream>>>(counts, offsets, partial);
  k_scan2<<<1, 256, 0, stream>>>(partial);
  k_scan3<<<NBLK, 256, 0, stream>>>(offsets, partial, cursor);
  k_scatter<<<(EL + 255) / 256, 256, 0, stream>>>(ei, cursor, srcs, eids);
  k_agg<<<N, 128, 0, stream>>>((const __half2*)xp, a_src, a_dst, srcs, offsets, bias,
                               (__half2*)hbuf);
  k_score<<<(N + 3) / 4, 256, 0, stream>>>((const __half2*)hbuf, srcs, eids, offsets,
                                           fc1W, fc1b, out);
}

// Round 4
// 831.199 us; speedup vs baseline: 1.4739x; 1.1635x over previous
//
#include <hip/hip_runtime.h>
#include <hip/hip_fp16.h>
#include <math.h>

// Problem constants
constexpr int N    = 50000;
constexpr int E    = 1600000;
constexpr int F    = 256;        // HEADS*HID
constexpr int EL   = E + N;      // edges + self loops
constexpr int NBLK = (N + 255) / 256;  // 196 scan blocks
#define TM 8

// ---------------------------------------------------------------------------
// Kernel 1: xp = x @ W  (fp32 math, LDS-staged, 8 nodes/block for W reuse)
// xp stored fp16; a_src/a_dst fp32 from the fp32 accumulator.
// Thread t owns output column t = h*64+c; wave w == head w.
// Inner loop reads xs as float4 (ds_read_b128) -> 4x fewer LDS instructions.
// ---------------------------------------------------------------------------
__global__ __launch_bounds__(256) void k_xw(
    const float* __restrict__ x, const float* __restrict__ W,
    const float* __restrict__ att_src, const float* __restrict__ att_dst,
    __half* __restrict__ xp, float* __restrict__ a_src, float* __restrict__ a_dst) {
  __shared__ float xs[TM][F];
  const int t  = threadIdx.x;
  const int n0 = blockIdx.x * TM;
  #pragma unroll
  for (int m = 0; m < TM; ++m) xs[m][t] = x[(size_t)(n0 + m) * F + t];
  __syncthreads();

  float acc[TM];
  #pragma unroll
  for (int m = 0; m < TM; ++m) acc[m] = 0.f;

  for (int k = 0; k < F; k += 4) {
    const float w0 = W[(k + 0) * F + t];
    const float w1 = W[(k + 1) * F + t];
    const float w2 = W[(k + 2) * F + t];
    const float w3 = W[(k + 3) * F + t];
    #pragma unroll
    for (int m = 0; m < TM; ++m) {
      const float4 xv = *(const float4*)&xs[m][k];
      acc[m] += xv.x * w0 + xv.y * w1 + xv.z * w2 + xv.w * w3;
    }
  }

  const int hd = t >> 6, lane = t & 63;
  const float asw = att_src[t];
  const float adw = att_dst[t];
  #pragma unroll
  for (int m = 0; m < TM; ++m) {
    const float v = acc[m];
    xp[(size_t)(n0 + m) * F + t] = __float2half_rn(v);
    float ps = v * asw, pd = v * adw;
    #pragma unroll
    for (int off = 32; off; off >>= 1) {
      ps += __shfl_down(ps, off, 64);
      pd += __shfl_down(pd, off, 64);
    }
    if (lane == 0) {
      a_src[(n0 + m) * 4 + hd] = ps;
      a_dst[(n0 + m) * 4 + hd] = pd;
    }
  }
}

// ---------------------------------------------------------------------------
// CSR construction: histogram -> 3-phase exclusive scan -> atomic scatter
// ---------------------------------------------------------------------------
__global__ void k_hist(const int* __restrict__ ei, int* __restrict__ counts) {
  const int i = blockIdx.x * blockDim.x + threadIdx.x;
  if (i < E) atomicAdd(&counts[ei[E + i]], 1);   // ei[E+i] = dst
}

__global__ __launch_bounds__(256) void k_scan1(
    const int* __restrict__ counts, int* __restrict__ offsets, int* __restrict__ partials) {
  __shared__ int s[256];
  const int t = threadIdx.x;
  const int i = blockIdx.x * 256 + t;
  const int v = (i < N) ? counts[i] + 1 : 0;     // +1 = self loop
  s[t] = v;
  __syncthreads();
  for (int off = 1; off < 256; off <<= 1) {
    const int add = (t >= off) ? s[t - off] : 0;
    __syncthreads();
    s[t] += add;
    __syncthreads();
  }
  if (i < N) offsets[i] = s[t] - v;              // local exclusive
  if (t == 255) partials[blockIdx.x] = s[255];   // block total
}

__global__ __launch_bounds__(256) void k_scan2(int* __restrict__ partials) {
  __shared__ int s[256];
  const int t = threadIdx.x;
  const int v = (t < NBLK) ? partials[t] : 0;
  s[t] = v;
  __syncthreads();
  for (int off = 1; off < 256; off <<= 1) {
    const int add = (t >= off) ? s[t - off] : 0;
    __syncthreads();
    s[t] += add;
    __syncthreads();
  }
  if (t < NBLK) partials[t] = s[t] - v;          // exclusive block offsets
}

__global__ void k_scan3(int* __restrict__ offsets, const int* __restrict__ partials,
                        int* __restrict__ cursor) {
  const int i = blockIdx.x * 256 + threadIdx.x;
  if (i < N) {
    const int v = offsets[i] + partials[blockIdx.x];
    offsets[i] = v;
    cursor[i]  = v;
  }
  if (i == 0) offsets[N] = EL;
}

__global__ void k_scatter(const int* __restrict__ ei, int* __restrict__ cursor,
                          int* __restrict__ srcs, int* __restrict__ eids) {
  const int i = blockIdx.x * blockDim.x + threadIdx.x;
  if (i >= EL) return;
  int s, d, id;
  if (i < E) { s = ei[i]; d = ei[E + i]; id = i; }
  else       { s = d = i - E; id = -1; }          // self loop: no score output
  const int pos = atomicAdd(&cursor[d], 1);
  srcs[pos] = s;
  eids[pos] = id;
}

// ---------------------------------------------------------------------------
// Segment softmax + aggregation + bias + leaky. One block (128 thr) per node.
// Thread t owns features {2t, 2t+1}; head = t>>5 -> 32-lane butterflies.
// ---------------------------------------------------------------------------
__global__ __launch_bounds__(128) void k_agg(
    const __half2* __restrict__ xp2, const float* __restrict__ a_src,
    const float* __restrict__ a_dst, const int* __restrict__ srcs,
    const int* __restrict__ offsets, const float* __restrict__ bias,
    __half2* __restrict__ h2) {
  const int n = blockIdx.x;
  const int t = threadIdx.x;              // 0..127
  const int hd = t >> 5;
  const int beg = offsets[n], end = offsets[n + 1];
  const float adst = a_dst[n * 4 + hd];

  float m = -1e30f;
  for (int i = beg + (t & 31); i < end; i += 32) {
    float al = a_src[srcs[i] * 4 + hd] + adst;
    al = al > 0.f ? al : 0.2f * al;
    m = fmaxf(m, al);
  }
  #pragma unroll
  for (int off = 16; off >= 1; off >>= 1) m = fmaxf(m, __shfl_xor(m, off, 64));

  float acc0 = 0.f, acc1 = 0.f, den = 0.f;
  int s_next = srcs[beg];
  for (int i = beg; i < end; ++i) {
    const int s = s_next;
    if (i + 1 < end) s_next = srcs[i + 1];
    const __half2 v = xp2[(size_t)s * 128 + t];   // issue gather early
    float al = a_src[s * 4 + hd] + adst;
    al = al > 0.f ? al : 0.2f * al;
    const float w = __expf(al - m);
    den += w;
    acc0 += w * __low2float(v);
    acc1 += w * __high2float(v);
  }
  const float inv = 1.f / (den + 1e-16f);
  float o0 = acc0 * inv + bias[2 * t];
  float o1 = acc1 * inv + bias[2 * t + 1];
  o0 = o0 > 0.f ? o0 : 0.01f * o0;
  o1 = o1 > 0.f ? o1 : 0.01f * o1;
  h2[(size_t)n * 128 + t] = __floats2half2_rn(o0, o1);
}

// ---------------------------------------------------------------------------
// Edge scoring, dst-grouped, 16 lanes per edge (4 edge slots per wave).
// Lane: sub = lane>>4 (edge slot), fl = lane&15 (owns features fl*16..+15).
// Per edge: one contiguous 512B src-row read (32B/lane over 16 lanes),
// 4-level butterfly (width 16) instead of 6-level over 64 lanes, and 4
// independent edges in flight per iteration -> latency-tolerant.
// h[dst] row and the lane's 48 fc1_W weights are register-resident.
// ---------------------------------------------------------------------------
__global__ __launch_bounds__(256) void k_score(
    const __half2* __restrict__ h2, const int* __restrict__ srcs,
    const int* __restrict__ eids, const int* __restrict__ offsets,
    const float* __restrict__ fc1W, const float* __restrict__ fc1b,
    float* __restrict__ out) {
  const int n = blockIdx.x * 4 + (threadIdx.x >> 6);   // one wave per dst node
  const int lane = threadIdx.x & 63;
  const int sub  = lane >> 4;
  const int fl   = lane & 15;

  // 48 weights for this lane's 16 features (fc1W row-major [256][3])
  float w[48];
  {
    const float4* wp = (const float4*)(fc1W + fl * 48);
    #pragma unroll
    for (int j = 0; j < 12; ++j) ((float4*)w)[j] = wp[j];
  }
  const float b0 = fc1b[0], b1 = fc1b[1], b2 = fc1b[2];

  // dst row features fl*16..fl*16+15, pre-scaled by 0.5
  float hd[16];
  {
    const uint4* dp = (const uint4*)(h2 + (size_t)n * 128 + fl * 8);
    const uint4 d0 = dp[0], d1 = dp[1];
    const __half2* a = (const __half2*)&d0;
    const __half2* b = (const __half2*)&d1;
    #pragma unroll
    for (int j = 0; j < 4; ++j) {
      hd[2 * j]     = __low2float(a[j])  * 0.5f;
      hd[2 * j + 1] = __high2float(a[j]) * 0.5f;
      hd[8 + 2 * j]     = __low2float(b[j])  * 0.5f;
      hd[8 + 2 * j + 1] = __high2float(b[j]) * 0.5f;
    }
  }

  const int beg = offsets[n], end = offsets[n + 1];
  for (int i0 = beg; i0 < end; i0 += 4) {
    const int i = i0 + sub;
    const bool act = (i < end);
    int s = 0, eid = -1;
    if (act) { s = srcs[i]; eid = eids[i]; }

    float p0 = 0.f, p1 = 0.f, p2 = 0.f;
    if (act) {
      const uint4* sp = (const uint4*)(h2 + (size_t)s * 128 + fl * 8);
      const uint4 s0 = sp[0], s1 = sp[1];
      const __half2* a = (const __half2*)&s0;
      const __half2* b = (const __half2*)&s1;
      float hs[16];
      #pragma unroll
      for (int j = 0; j < 4; ++j) {
        hs[2 * j]     = __low2float(a[j]);
        hs[2 * j + 1] = __high2float(a[j]);
        hs[8 + 2 * j]     = __low2float(b[j]);
        hs[8 + 2 * j + 1] = __high2float(b[j]);
      }
      #pragma unroll
      for (int j = 0; j < 16; ++j) {
        const float r = hs[j] * hd[j];
        p0 += r * w[3 * j + 0];
        p1 += r * w[3 * j + 1];
        p2 += r * w[3 * j + 2];
      }
    }
    #pragma unroll
    for (int off = 1; off < 16; off <<= 1) {
      p0 += __shfl_xor(p0, off, 16);
      p1 += __shfl_xor(p1, off, 16);
      p2 += __shfl_xor(p2, off, 16);
    }
    if (act && eid >= 0 && fl == 0) {
      out[(size_t)eid * 3 + 0] = p0 + b0;
      out[(size_t)eid * 3 + 1] = p1 + b1;
      out[(size_t)eid * 3 + 2] = p2 + b2;
    }
  }
}

// ---------------------------------------------------------------------------
static inline size_t align256(size_t b) { return (b + 255) & ~(size_t)255; }

extern "C" void kernel_launch(void* const* d_in, const int* in_sizes, int n_in,
                              void* d_out, int out_size, void* d_ws, size_t ws_size,
                              hipStream_t stream) {
  const float* x    = (const float*)d_in[0];
  const int*   ei   = (const int*)  d_in[1];   // [2,E] flat: [0:E]=src, [E:2E]=dst
  const float* W    = (const float*)d_in[2];
  const float* attS = (const float*)d_in[3];
  const float* attD = (const float*)d_in[4];
  const float* bias = (const float*)d_in[5];
  const float* fc1W = (const float*)d_in[6];
  const float* fc1b = (const float*)d_in[7];
  float*       out  = (float*)d_out;
  char*        ws   = (char*)d_ws;

  size_t off = 0;
  auto alloc = [&](size_t bytes) -> void* {
    void* p = ws + off;
    off += align256(bytes);
    return p;
  };
  __half* xp      = (__half*)alloc((size_t)N * F * sizeof(__half));  // 25.6 MB
  __half* hbuf    = (__half*)alloc((size_t)N * F * sizeof(__half));  // 25.6 MB
  float*  a_src   = (float*) alloc((size_t)N * 4 * sizeof(float));
  float*  a_dst   = (float*) alloc((size_t)N * 4 * sizeof(float));
  int*    counts  = (int*)   alloc((size_t)N * sizeof(int));
  int*    offsets = (int*)   alloc((size_t)(N + 1) * sizeof(int));
  int*    partial = (int*)   alloc(256 * sizeof(int));
  int*    cursor  = (int*)   alloc((size_t)N * sizeof(int));
  int*    srcs    = (int*)   alloc((size_t)EL * sizeof(int));        // 6.6 MB
  int*    eids    = (int*)   alloc((size_t)EL * sizeof(int));        // 6.6 MB

  hipMemsetAsync(counts, 0, (size_t)N * sizeof(int), stream);

  k_xw<<<N / TM, 256, 0, stream>>>(x, W, attS, attD, xp, a_src, a_dst);
  k_hist<<<(E + 255) / 256, 256, 0, stream>>>(ei, counts);
  k_scan1<<<NBLK, 256, 0, stream>>>(counts, offsets, partial);
  k_scan2<<<1, 256, 0, stream>>>(partial);
  k_scan3<<<NBLK, 256, 0, stream>>>(offsets, partial, cursor);
  k_scatter<<<(EL + 255) / 256, 256, 0, stream>>>(ei, cursor, srcs, eids);
  k_agg<<<N, 128, 0, stream>>>((const __half2*)xp, a_src, a_dst, srcs, offsets, bias,
                               (__half2*)hbuf);
  k_score<<<(N + 3) / 4, 256, 0, stream>>>((const __half2*)hbuf, srcs, eids, offsets,
                                           fc1W, fc1b, out);
}

// Round 5
// 666.409 us; speedup vs baseline: 1.8384x; 1.2473x over previous
//
#include <hip/hip_runtime.h>
#include <hip/hip_fp16.h>
#include <math.h>

// Problem constants
constexpr int N    = 50000;
constexpr int E    = 1600000;
constexpr int F    = 256;        // HEADS*HID
constexpr int EL   = E + N;      // edges + self loops
constexpr int NBLK = (N + 255) / 256;  // 196 scan blocks

typedef _Float16 v8hf __attribute__((ext_vector_type(8)));
typedef float    v4f  __attribute__((ext_vector_type(4)));

// ---------------------------------------------------------------------------
// fp32 -> fp16 conversions for the MFMA GEMM inputs.
// ---------------------------------------------------------------------------
__global__ void k_cvt_x(const float* __restrict__ x, _Float16* __restrict__ xh) {
  const size_t i = ((size_t)blockIdx.x * 256 + threadIdx.x) * 4;   // N*F divisible
  const float4 v = *(const float4*)(x + i);
  _Float16 h[4] = {(_Float16)v.x, (_Float16)v.y, (_Float16)v.z, (_Float16)v.w};
  *(uint2*)(xh + i) = *(const uint2*)h;
}

// wt[n*256+k] = W[k*256+n]  (transposed so B-fragment loads are 16B contiguous)
__global__ void k_cvt_w(const float* __restrict__ W, _Float16* __restrict__ wt) {
  const int id = blockIdx.x * 256 + threadIdx.x;   // 65536 total
  const int n = id >> 8, k = id & 255;
  wt[id] = (_Float16)W[k * 256 + n];
}

// ---------------------------------------------------------------------------
// xp = x @ W via MFMA 16x16x32 f16 (fp32 accumulate).
// Block = 256 thr = 4 waves; wave w owns cols 64w..64w+63 (== head w) of a
// 16-row strip. Epilogue: xp stored fp16; a_src/a_dst computed from the fp32
// accumulators (attention logits stay near-fp32 accuracy).
// Layouts (guide §3, m89-verified): A[m=lane&15][k=q*8+j], B[k=q*8+j][n=lane&15],
// C col=lane&15, row=q*4+reg.
// ---------------------------------------------------------------------------
__global__ __launch_bounds__(256) void k_xw_mfma(
    const _Float16* __restrict__ xh, const _Float16* __restrict__ wt,
    const float* __restrict__ att_src, const float* __restrict__ att_dst,
    __half* __restrict__ xp, float* __restrict__ a_src, float* __restrict__ a_dst) {
  const int wv   = threadIdx.x >> 6;      // wave id = head = col-group
  const int lane = threadIdx.x & 63;
  const int q = lane >> 4, l16 = lane & 15;
  const int m0 = blockIdx.x * 16;
  const int c0 = wv * 64;

  v4f acc[4] = {{0,0,0,0},{0,0,0,0},{0,0,0,0},{0,0,0,0}};
  const _Float16* arow = xh + (size_t)(m0 + l16) * 256 + q * 8;
  const _Float16* brow = wt + (size_t)(c0 + l16) * 256 + q * 8;

  for (int kc = 0; kc < 256; kc += 32) {
    const v8hf a = *(const v8hf*)(arow + kc);
    #pragma unroll
    for (int tn = 0; tn < 4; ++tn) {
      const v8hf b = *(const v8hf*)(brow + (size_t)tn * 16 * 256 + kc);
      acc[tn] = __builtin_amdgcn_mfma_f32_16x16x32_f16(a, b, acc[tn], 0, 0, 0);
    }
  }

  // store xp (fp16): row = m0 + q*4 + r, col = c0 + tn*16 + l16
  #pragma unroll
  for (int tn = 0; tn < 4; ++tn) {
    const int col = c0 + tn * 16 + l16;
    #pragma unroll
    for (int r = 0; r < 4; ++r)
      xp[(size_t)(m0 + q * 4 + r) * 256 + col] = __float2half_rn(acc[tn][r]);
  }

  // attention logits from fp32 accs: a_src[n][wv] = sum_col C[n][col]*attS[col]
  float aw[4], dw[4];
  #pragma unroll
  for (int tn = 0; tn < 4; ++tn) {
    aw[tn] = att_src[c0 + tn * 16 + l16];
    dw[tn] = att_dst[c0 + tn * 16 + l16];
  }
  #pragma unroll
  for (int r = 0; r < 4; ++r) {
    float ps = acc[0][r]*aw[0] + acc[1][r]*aw[1] + acc[2][r]*aw[2] + acc[3][r]*aw[3];
    float pd = acc[0][r]*dw[0] + acc[1][r]*dw[1] + acc[2][r]*dw[2] + acc[3][r]*dw[3];
    #pragma unroll
    for (int off = 1; off < 16; off <<= 1) {
      ps += __shfl_xor(ps, off, 16);
      pd += __shfl_xor(pd, off, 16);
    }
    if (l16 == 0) {
      a_src[(m0 + q * 4 + r) * 4 + wv] = ps;
      a_dst[(m0 + q * 4 + r) * 4 + wv] = pd;
    }
  }
}

// ---------------------------------------------------------------------------
// CSR construction: histogram -> 3-phase exclusive scan -> atomic scatter
// ---------------------------------------------------------------------------
__global__ void k_hist(const int* __restrict__ ei, int* __restrict__ counts) {
  const int i = blockIdx.x * blockDim.x + threadIdx.x;
  if (i < E) atomicAdd(&counts[ei[E + i]], 1);   // ei[E+i] = dst
}

__global__ __launch_bounds__(256) void k_scan1(
    const int* __restrict__ counts, int* __restrict__ offsets, int* __restrict__ partials) {
  __shared__ int s[256];
  const int t = threadIdx.x;
  const int i = blockIdx.x * 256 + t;
  const int v = (i < N) ? counts[i] + 1 : 0;     // +1 = self loop
  s[t] = v;
  __syncthreads();
  for (int off = 1; off < 256; off <<= 1) {
    const int add = (t >= off) ? s[t - off] : 0;
    __syncthreads();
    s[t] += add;
    __syncthreads();
  }
  if (i < N) offsets[i] = s[t] - v;              // local exclusive
  if (t == 255) partials[blockIdx.x] = s[255];   // block total
}

__global__ __launch_bounds__(256) void k_scan2(int* __restrict__ partials) {
  __shared__ int s[256];
  const int t = threadIdx.x;
  const int v = (t < NBLK) ? partials[t] : 0;
  s[t] = v;
  __syncthreads();
  for (int off = 1; off < 256; off <<= 1) {
    const int add = (t >= off) ? s[t - off] : 0;
    __syncthreads();
    s[t] += add;
    __syncthreads();
  }
  if (t < NBLK) partials[t] = s[t] - v;          // exclusive block offsets
}

__global__ void k_scan3(int* __restrict__ offsets, const int* __restrict__ partials,
                        int* __restrict__ cursor) {
  const int i = blockIdx.x * 256 + threadIdx.x;
  if (i < N) {
    const int v = offsets[i] + partials[blockIdx.x];
    offsets[i] = v;
    cursor[i]  = v;
  }
  if (i == 0) offsets[N] = EL;
}

__global__ void k_scatter(const int* __restrict__ ei, int* __restrict__ cursor,
                          int* __restrict__ srcs, int* __restrict__ eids) {
  const int i = blockIdx.x * blockDim.x + threadIdx.x;
  if (i >= EL) return;
  int s, d, id;
  if (i < E) { s = ei[i]; d = ei[E + i]; id = i; }
  else       { s = d = i - E; id = -1; }          // self loop: no score output
  const int pos = atomicAdd(&cursor[d], 1);
  srcs[pos] = s;
  eids[pos] = id;
}

// ---------------------------------------------------------------------------
// Segment softmax + aggregation + bias + leaky. One WAVE per node (2/block).
// Lane owns features 4L..4L+3 (one 8B load/edge; wave covers full 512B row).
// Softmax is shift-invariant and logits are bounded (|al|<~8) -> no max pass.
// Weights: 16 lane-slots x 4 heads compute w once per (edge,head); broadcast
// via __shfl width 16 (wave-synchronous, no LDS, no barriers). Gather loop
// unrolled x4 -> 4 independent loads in flight.
// ---------------------------------------------------------------------------
__global__ __launch_bounds__(128) void k_agg(
    const __half* __restrict__ xp, const float* __restrict__ a_src,
    const float* __restrict__ a_dst, const int* __restrict__ srcs,
    const int* __restrict__ offsets, const float* __restrict__ bias,
    __half* __restrict__ h) {
  const int n = blockIdx.x * 2 + (threadIdx.x >> 6);
  const int lane = threadIdx.x & 63;
  const int hd = lane >> 4, es = lane & 15;
  const int beg = offsets[n], end = offsets[n + 1];
  const float adst = a_dst[n * 4 + hd];
  const __half* xb = xp + (size_t)lane * 4;

  float a0 = 0.f, a1 = 0.f, a2 = 0.f, a3 = 0.f, den = 0.f;

  for (int c = beg; c < end; c += 16) {
    const int cnt = min(16, end - c);
    int sv = 0; float wvv = 0.f;
    if (es < cnt) {
      sv = srcs[c + es];
      float al = a_src[sv * 4 + hd] + adst;
      al = al > 0.f ? al : 0.2f * al;
      wvv = __expf(al);
    }
    int j = 0;
    for (; j + 4 <= cnt; j += 4) {
      const int   s0 = __shfl(sv, j + 0, 16), s1 = __shfl(sv, j + 1, 16);
      const int   s2 = __shfl(sv, j + 2, 16), s3 = __shfl(sv, j + 3, 16);
      const float w0 = __shfl(wvv, j + 0, 16), w1 = __shfl(wvv, j + 1, 16);
      const float w2 = __shfl(wvv, j + 2, 16), w3 = __shfl(wvv, j + 3, 16);
      const uint2 r0 = *(const uint2*)(xb + (size_t)s0 * 256);
      const uint2 r1 = *(const uint2*)(xb + (size_t)s1 * 256);
      const uint2 r2 = *(const uint2*)(xb + (size_t)s2 * 256);
      const uint2 r3 = *(const uint2*)(xb + (size_t)s3 * 256);
      den += (w0 + w1) + (w2 + w3);
      {
        const __half2* p = (const __half2*)&r0;
        const float2 lo = __half22float2(p[0]), hi = __half22float2(p[1]);
        a0 += w0 * lo.x; a1 += w0 * lo.y; a2 += w0 * hi.x; a3 += w0 * hi.y;
      }
      {
        const __half2* p = (const __half2*)&r1;
        const float2 lo = __half22float2(p[0]), hi = __half22float2(p[1]);
        a0 += w1 * lo.x; a1 += w1 * lo.y; a2 += w1 * hi.x; a3 += w1 * hi.y;
      }
      {
        const __half2* p = (const __half2*)&r2;
        const float2 lo = __half22float2(p[0]), hi = __half22float2(p[1]);
        a0 += w2 * lo.x; a1 += w2 * lo.y; a2 += w2 * hi.x; a3 += w2 * hi.y;
      }
      {
        const __half2* p = (const __half2*)&r3;
        const float2 lo = __half22float2(p[0]), hi = __half22float2(p[1]);
        a0 += w3 * lo.x; a1 += w3 * lo.y; a2 += w3 * hi.x; a3 += w3 * hi.y;
      }
    }
    for (; j < cnt; ++j) {
      const int   s = __shfl(sv, j, 16);
      const float w = __shfl(wvv, j, 16);
      const uint2 r = *(const uint2*)(xb + (size_t)s * 256);
      const __half2* p = (const __half2*)&r;
      const float2 lo = __half22float2(p[0]), hi = __half22float2(p[1]);
      den += w;
      a0 += w * lo.x; a1 += w * lo.y; a2 += w * hi.x; a3 += w * hi.y;
    }
  }

  const float inv = 1.f / (den + 1e-16f);
  const float4 bv = *(const float4*)(bias + lane * 4);
  float o0 = a0 * inv + bv.x, o1 = a1 * inv + bv.y;
  float o2 = a2 * inv + bv.z, o3 = a3 * inv + bv.w;
  o0 = o0 > 0.f ? o0 : 0.01f * o0;
  o1 = o1 > 0.f ? o1 : 0.01f * o1;
  o2 = o2 > 0.f ? o2 : 0.01f * o2;
  o3 = o3 > 0.f ? o3 : 0.01f * o3;
  const __half2 p0 = __floats2half2_rn(o0, o1), p1 = __floats2half2_rn(o2, o3);
  uint2 st;
  st.x = *(const unsigned*)&p0;
  st.y = *(const unsigned*)&p1;
  *(uint2*)(h + (size_t)n * 256 + lane * 4) = st;
}

// ---------------------------------------------------------------------------
// Edge scoring, dst-grouped, 16 lanes per edge (4 edge slots per wave).
// ---------------------------------------------------------------------------
__global__ __launch_bounds__(256) void k_score(
    const __half2* __restrict__ h2, const int* __restrict__ srcs,
    const int* __restrict__ eids, const int* __restrict__ offsets,
    const float* __restrict__ fc1W, const float* __restrict__ fc1b,
    float* __restrict__ out) {
  const int n = blockIdx.x * 4 + (threadIdx.x >> 6);   // one wave per dst node
  const int lane = threadIdx.x & 63;
  const int sub  = lane >> 4;
  const int fl   = lane & 15;

  float w[48];
  {
    const float4* wp = (const float4*)(fc1W + fl * 48);
    #pragma unroll
    for (int j = 0; j < 12; ++j) ((float4*)w)[j] = wp[j];
  }
  const float b0 = fc1b[0], b1 = fc1b[1], b2 = fc1b[2];

  float hd[16];
  {
    const uint4* dp = (const uint4*)(h2 + (size_t)n * 128 + fl * 8);
    const uint4 d0 = dp[0], d1 = dp[1];
    const __half2* a = (const __half2*)&d0;
    const __half2* b = (const __half2*)&d1;
    #pragma unroll
    for (int j = 0; j < 4; ++j) {
      hd[2 * j]     = __low2float(a[j])  * 0.5f;
      hd[2 * j + 1] = __high2float(a[j]) * 0.5f;
      hd[8 + 2 * j]     = __low2float(b[j])  * 0.5f;
      hd[8 + 2 * j + 1] = __high2float(b[j]) * 0.5f;
    }
  }

  const int beg = offsets[n], end = offsets[n + 1];
  for (int i0 = beg; i0 < end; i0 += 4) {
    const int i = i0 + sub;
    const bool act = (i < end);
    int s = 0, eid = -1;
    if (act) { s = srcs[i]; eid = eids[i]; }

    float p0 = 0.f, p1 = 0.f, p2 = 0.f;
    if (act) {
      const uint4* sp = (const uint4*)(h2 + (size_t)s * 128 + fl * 8);
      const uint4 s0 = sp[0], s1 = sp[1];
      const __half2* a = (const __half2*)&s0;
      const __half2* b = (const __half2*)&s1;
      float hs[16];
      #pragma unroll
      for (int j = 0; j < 4; ++j) {
        hs[2 * j]     = __low2float(a[j]);
        hs[2 * j + 1] = __high2float(a[j]);
        hs[8 + 2 * j]     = __low2float(b[j]);
        hs[8 + 2 * j + 1] = __high2float(b[j]);
      }
      #pragma unroll
      for (int j = 0; j < 16; ++j) {
        const float r = hs[j] * hd[j];
        p0 += r * w[3 * j + 0];
        p1 += r * w[3 * j + 1];
        p2 += r * w[3 * j + 2];
      }
    }
    #pragma unroll
    for (int off = 1; off < 16; off <<= 1) {
      p0 += __shfl_xor(p0, off, 16);
      p1 += __shfl_xor(p1, off, 16);
      p2 += __shfl_xor(p2, off, 16);
    }
    if (act && eid >= 0 && fl == 0) {
      out[(size_t)eid * 3 + 0] = p0 + b0;
      out[(size_t)eid * 3 + 1] = p1 + b1;
      out[(size_t)eid * 3 + 2] = p2 + b2;
    }
  }
}

// ---------------------------------------------------------------------------
static inline size_t align256(size_t b) { return (b + 255) & ~(size_t)255; }

extern "C" void kernel_launch(void* const* d_in, const int* in_sizes, int n_in,
                              void* d_out, int out_size, void* d_ws, size_t ws_size,
                              hipStream_t stream) {
  const float* x    = (const float*)d_in[0];
  const int*   ei   = (const int*)  d_in[1];   // [2,E] flat: [0:E]=src, [E:2E]=dst
  const float* W    = (const float*)d_in[2];
  const float* attS = (const float*)d_in[3];
  const float* attD = (const float*)d_in[4];
  const float* bias = (const float*)d_in[5];
  const float* fc1W = (const float*)d_in[6];
  const float* fc1b = (const float*)d_in[7];
  float*       out  = (float*)d_out;
  char*        ws   = (char*)d_ws;

  size_t off = 0;
  auto alloc = [&](size_t bytes) -> void* {
    void* p = ws + off;
    off += align256(bytes);
    return p;
  };
  _Float16* xh     = (_Float16*)alloc((size_t)N * F * sizeof(_Float16)); // 25.6 MB
  _Float16* wt     = (_Float16*)alloc((size_t)F * F * sizeof(_Float16)); // 128 KB
  __half*   xp     = (__half*)  alloc((size_t)N * F * sizeof(__half));   // 25.6 MB
  __half*   hbuf   = (__half*)  alloc((size_t)N * F * sizeof(__half));   // 25.6 MB
  float*    a_src  = (float*)   alloc((size_t)N * 4 * sizeof(float));
  float*    a_dst  = (float*)   alloc((size_t)N * 4 * sizeof(float));
  int*      counts = (int*)     alloc((size_t)N * sizeof(int));
  int*      offs   = (int*)     alloc((size_t)(N + 1) * sizeof(int));
  int*      partial= (int*)     alloc(256 * sizeof(int));
  int*      cursor = (int*)     alloc((size_t)N * sizeof(int));
  int*      srcs   = (int*)     alloc((size_t)EL * sizeof(int));         // 6.6 MB
  int*      eids   = (int*)     alloc((size_t)EL * sizeof(int));         // 6.6 MB

  hipMemsetAsync(counts, 0, (size_t)N * sizeof(int), stream);

  k_cvt_x<<<(N * F / 4 + 255) / 256, 256, 0, stream>>>(x, xh);
  k_cvt_w<<<F * F / 256, 256, 0, stream>>>(W, wt);
  k_xw_mfma<<<N / 16, 256, 0, stream>>>(xh, wt, attS, attD, xp, a_src, a_dst);
  k_hist<<<(E + 255) / 256, 256, 0, stream>>>(ei, counts);
  k_scan1<<<NBLK, 256, 0, stream>>>(counts, offs, partial);
  k_scan2<<<1, 256, 0, stream>>>(partial);
  k_scan3<<<NBLK, 256, 0, stream>>>(offs, partial, cursor);
  k_scatter<<<(EL + 255) / 256, 256, 0, stream>>>(ei, cursor, srcs, eids);
  k_agg<<<N / 2, 128, 0, stream>>>(xp, a_src, a_dst, srcs, offs, bias, hbuf);
  k_score<<<(N + 3) / 4, 256, 0, stream>>>((const __half2*)hbuf, srcs, eids, offs,
                                           fc1W, fc1b, out);
}

// Round 6
// 664.989 us; speedup vs baseline: 1.8423x; 1.0021x over previous
//
#include <hip/hip_runtime.h>
#include <hip/hip_fp16.h>
#include <math.h>

// Problem constants
constexpr int N    = 50000;
constexpr int E    = 1600000;
constexpr int F    = 256;        // HEADS*HID
constexpr int EL   = E + N;      // edges + self loops
constexpr int NBLK = (N + 255) / 256;  // 196 scan blocks

typedef _Float16 v8hf __attribute__((ext_vector_type(8)));
typedef float    v4f  __attribute__((ext_vector_type(4)));

// ---------------------------------------------------------------------------
// fp32 -> fp16 conversions for the MFMA GEMM inputs.
// ---------------------------------------------------------------------------
__global__ void k_cvt_x(const float* __restrict__ x, _Float16* __restrict__ xh) {
  const size_t i = ((size_t)blockIdx.x * 256 + threadIdx.x) * 4;   // N*F divisible
  const float4 v = *(const float4*)(x + i);
  _Float16 h[4] = {(_Float16)v.x, (_Float16)v.y, (_Float16)v.z, (_Float16)v.w};
  *(uint2*)(xh + i) = *(const uint2*)h;
}

// wt[n*256+k] = W[k*256+n]  (transposed so B-fragment loads are 16B contiguous)
__global__ void k_cvt_w(const float* __restrict__ W, _Float16* __restrict__ wt) {
  const int id = blockIdx.x * 256 + threadIdx.x;   // 65536 total
  const int n = id >> 8, k = id & 255;
  wt[id] = (_Float16)W[k * 256 + n];
}

// wt3h[n*256+k] = n<3 ? (half)(0.5*fc1W[k*3+n]) : 0   (B for score MFMA;
// the edge_rep 0.5 factor is folded here — exact pow-2 scale)
__global__ void k_cvt_w3(const float* __restrict__ fc1W, _Float16* __restrict__ wt3h) {
  const int id = blockIdx.x * 256 + threadIdx.x;   // 4096 total
  const int n = id >> 8, k = id & 255;
  wt3h[id] = (n < 3) ? (_Float16)(0.5f * fc1W[k * 3 + n]) : (_Float16)0.f;
}

// ---------------------------------------------------------------------------
// xp = x @ W via MFMA 16x16x32 f16 (fp32 accumulate).
// Block = 256 thr = 4 waves; wave w owns cols 64w..64w+63 (== head w) of a
// 16-row strip. Epilogue: xp stored fp16; a_src/a_dst computed from the fp32
// accumulators (attention logits stay near-fp32 accuracy).
// Layouts (guide §3, m89-verified): A[m=lane&15][k=q*8+j], B[k=q*8+j][n=lane&15],
// C col=lane&15, row=q*4+reg.
// ---------------------------------------------------------------------------
__global__ __launch_bounds__(256) void k_xw_mfma(
    const _Float16* __restrict__ xh, const _Float16* __restrict__ wt,
    const float* __restrict__ att_src, const float* __restrict__ att_dst,
    __half* __restrict__ xp, float* __restrict__ a_src, float* __restrict__ a_dst) {
  const int wv   = threadIdx.x >> 6;      // wave id = head = col-group
  const int lane = threadIdx.x & 63;
  const int q = lane >> 4, l16 = lane & 15;
  const int m0 = blockIdx.x * 16;
  const int c0 = wv * 64;

  v4f acc[4] = {{0,0,0,0},{0,0,0,0},{0,0,0,0},{0,0,0,0}};
  const _Float16* arow = xh + (size_t)(m0 + l16) * 256 + q * 8;
  const _Float16* brow = wt + (size_t)(c0 + l16) * 256 + q * 8;

  for (int kc = 0; kc < 256; kc += 32) {
    const v8hf a = *(const v8hf*)(arow + kc);
    #pragma unroll
    for (int tn = 0; tn < 4; ++tn) {
      const v8hf b = *(const v8hf*)(brow + (size_t)tn * 16 * 256 + kc);
      acc[tn] = __builtin_amdgcn_mfma_f32_16x16x32_f16(a, b, acc[tn], 0, 0, 0);
    }
  }

  // store xp (fp16): row = m0 + q*4 + r, col = c0 + tn*16 + l16
  #pragma unroll
  for (int tn = 0; tn < 4; ++tn) {
    const int col = c0 + tn * 16 + l16;
    #pragma unroll
    for (int r = 0; r < 4; ++r)
      xp[(size_t)(m0 + q * 4 + r) * 256 + col] = __float2half_rn(acc[tn][r]);
  }

  // attention logits from fp32 accs: a_src[n][wv] = sum_col C[n][col]*attS[col]
  float aw[4], dw[4];
  #pragma unroll
  for (int tn = 0; tn < 4; ++tn) {
    aw[tn] = att_src[c0 + tn * 16 + l16];
    dw[tn] = att_dst[c0 + tn * 16 + l16];
  }
  #pragma unroll
  for (int r = 0; r < 4; ++r) {
    float ps = acc[0][r]*aw[0] + acc[1][r]*aw[1] + acc[2][r]*aw[2] + acc[3][r]*aw[3];
    float pd = acc[0][r]*dw[0] + acc[1][r]*dw[1] + acc[2][r]*dw[2] + acc[3][r]*dw[3];
    #pragma unroll
    for (int off = 1; off < 16; off <<= 1) {
      ps += __shfl_xor(ps, off, 16);
      pd += __shfl_xor(pd, off, 16);
    }
    if (l16 == 0) {
      a_src[(m0 + q * 4 + r) * 4 + wv] = ps;
      a_dst[(m0 + q * 4 + r) * 4 + wv] = pd;
    }
  }
}

// ---------------------------------------------------------------------------
// CSR construction: histogram -> 3-phase exclusive scan -> atomic scatter
// ---------------------------------------------------------------------------
__global__ void k_hist(const int* __restrict__ ei, int* __restrict__ counts) {
  const int i = blockIdx.x * blockDim.x + threadIdx.x;
  if (i < E) atomicAdd(&counts[ei[E + i]], 1);   // ei[E+i] = dst
}

__global__ __launch_bounds__(256) void k_scan1(
    const int* __restrict__ counts, int* __restrict__ offsets, int* __restrict__ partials) {
  __shared__ int s[256];
  const int t = threadIdx.x;
  const int i = blockIdx.x * 256 + t;
  const int v = (i < N) ? counts[i] + 1 : 0;     // +1 = self loop
  s[t] = v;
  __syncthreads();
  for (int off = 1; off < 256; off <<= 1) {
    const int add = (t >= off) ? s[t - off] : 0;
    __syncthreads();
    s[t] += add;
    __syncthreads();
  }
  if (i < N) offsets[i] = s[t] - v;              // local exclusive
  if (t == 255) partials[blockIdx.x] = s[255];   // block total
}

__global__ __launch_bounds__(256) void k_scan2(int* __restrict__ partials) {
  __shared__ int s[256];
  const int t = threadIdx.x;
  const int v = (t < NBLK) ? partials[t] : 0;
  s[t] = v;
  __syncthreads();
  for (int off = 1; off < 256; off <<= 1) {
    const int add = (t >= off) ? s[t - off] : 0;
    __syncthreads();
    s[t] += add;
    __syncthreads();
  }
  if (t < NBLK) partials[t] = s[t] - v;          // exclusive block offsets
}

__global__ void k_scan3(int* __restrict__ offsets, const int* __restrict__ partials,
                        int* __restrict__ cursor) {
  const int i = blockIdx.x * 256 + threadIdx.x;
  if (i < N) {
    const int v = offsets[i] + partials[blockIdx.x];
    offsets[i] = v;
    cursor[i]  = v;
  }
  if (i == 0) offsets[N] = EL;
}

// se[pos] = (src, eid); eid=-1 for self loops (no score output)
__global__ void k_scatter(const int* __restrict__ ei, int* __restrict__ cursor,
                          int2* __restrict__ se) {
  const int i = blockIdx.x * blockDim.x + threadIdx.x;
  if (i >= EL) return;
  int s, d, id;
  if (i < E) { s = ei[i]; d = ei[E + i]; id = i; }
  else       { s = d = i - E; id = -1; }
  const int pos = atomicAdd(&cursor[d], 1);
  se[pos] = make_int2(s, id);
}

// ---------------------------------------------------------------------------
// Segment softmax + aggregation + bias + leaky. One WAVE per node (2/block).
// Lane owns features 4L..4L+3 (one 8B load/edge; wave covers full 512B row).
// Softmax is shift-invariant and logits are bounded -> no max pass (fp32 exp).
// Weights: 16 lane-slots x 4 heads compute w once per (edge,head); broadcast
// via __shfl width 16. Gather loop unrolled x4 -> 4 loads in flight.
// ---------------------------------------------------------------------------
__global__ __launch_bounds__(128) void k_agg(
    const __half* __restrict__ xp, const float* __restrict__ a_src,
    const float* __restrict__ a_dst, const int2* __restrict__ se,
    const int* __restrict__ offsets, const float* __restrict__ bias,
    __half* __restrict__ h) {
  const int n = blockIdx.x * 2 + (threadIdx.x >> 6);
  const int lane = threadIdx.x & 63;
  const int hd = lane >> 4, es = lane & 15;
  const int beg = offsets[n], end = offsets[n + 1];
  const float adst = a_dst[n * 4 + hd];
  const __half* xb = xp + (size_t)lane * 4;

  float a0 = 0.f, a1 = 0.f, a2 = 0.f, a3 = 0.f, den = 0.f;

  for (int c = beg; c < end; c += 16) {
    const int cnt = min(16, end - c);
    int sv = 0; float wvv = 0.f;
    if (es < cnt) {
      sv = se[c + es].x;
      float al = a_src[sv * 4 + hd] + adst;
      al = al > 0.f ? al : 0.2f * al;
      wvv = __expf(al);
    }
    int j = 0;
    for (; j + 4 <= cnt; j += 4) {
      const int   s0 = __shfl(sv, j + 0, 16), s1 = __shfl(sv, j + 1, 16);
      const int   s2 = __shfl(sv, j + 2, 16), s3 = __shfl(sv, j + 3, 16);
      const float w0 = __shfl(wvv, j + 0, 16), w1 = __shfl(wvv, j + 1, 16);
      const float w2 = __shfl(wvv, j + 2, 16), w3 = __shfl(wvv, j + 3, 16);
      const uint2 r0 = *(const uint2*)(xb + (size_t)s0 * 256);
      const uint2 r1 = *(const uint2*)(xb + (size_t)s1 * 256);
      const uint2 r2 = *(const uint2*)(xb + (size_t)s2 * 256);
      const uint2 r3 = *(const uint2*)(xb + (size_t)s3 * 256);
      den += (w0 + w1) + (w2 + w3);
      {
        const __half2* p = (const __half2*)&r0;
        const float2 lo = __half22float2(p[0]), hi = __half22float2(p[1]);
        a0 += w0 * lo.x; a1 += w0 * lo.y; a2 += w0 * hi.x; a3 += w0 * hi.y;
      }
      {
        const __half2* p = (const __half2*)&r1;
        const float2 lo = __half22float2(p[0]), hi = __half22float2(p[1]);
        a0 += w1 * lo.x; a1 += w1 * lo.y; a2 += w1 * hi.x; a3 += w1 * hi.y;
      }
      {
        const __half2* p = (const __half2*)&r2;
        const float2 lo = __half22float2(p[0]), hi = __half22float2(p[1]);
        a0 += w2 * lo.x; a1 += w2 * lo.y; a2 += w2 * hi.x; a3 += w2 * hi.y;
      }
      {
        const __half2* p = (const __half2*)&r3;
        const float2 lo = __half22float2(p[0]), hi = __half22float2(p[1]);
        a0 += w3 * lo.x; a1 += w3 * lo.y; a2 += w3 * hi.x; a3 += w3 * hi.y;
      }
    }
    for (; j < cnt; ++j) {
      const int   s = __shfl(sv, j, 16);
      const float w = __shfl(wvv, j, 16);
      const uint2 r = *(const uint2*)(xb + (size_t)s * 256);
      const __half2* p = (const __half2*)&r;
      const float2 lo = __half22float2(p[0]), hi = __half22float2(p[1]);
      den += w;
      a0 += w * lo.x; a1 += w * lo.y; a2 += w * hi.x; a3 += w * hi.y;
    }
  }

  const float inv = 1.f / (den + 1e-16f);
  const float4 bv = *(const float4*)(bias + lane * 4);
  float o0 = a0 * inv + bv.x, o1 = a1 * inv + bv.y;
  float o2 = a2 * inv + bv.z, o3 = a3 * inv + bv.w;
  o0 = o0 > 0.f ? o0 : 0.01f * o0;
  o1 = o1 > 0.f ? o1 : 0.01f * o1;
  o2 = o2 > 0.f ? o2 : 0.01f * o2;
  o3 = o3 > 0.f ? o3 : 0.01f * o3;
  const __half2 p0 = __floats2half2_rn(o0, o1), p1 = __floats2half2_rn(o2, o3);
  uint2 st;
  st.x = *(const unsigned*)&p0;
  st.y = *(const unsigned*)&p1;
  *(uint2*)(h + (size_t)n * 256 + lane * 4) = st;
}

// ---------------------------------------------------------------------------
// Edge scoring via MFMA. One wave per dst node; 16 edges per chunk.
// A[m=l16][k=q*8+j] = h[src_m][k] * h[n][k]  (packed fp16 mul),
// B[k][nn=l16] = wt3h (0.5*fc1W^T fp16, cols 3..15 zero),
// C: col=l16 (score idx), row=q*4+r (edge slot). 8 MFMAs cover K=256.
// Per 16 edges: 8 independent dwordx4 gathers, 32 pk_mul, 8 MFMA.
// ---------------------------------------------------------------------------
__global__ __launch_bounds__(256) void k_score_mfma(
    const _Float16* __restrict__ h, const int2* __restrict__ se,
    const int* __restrict__ offsets, const _Float16* __restrict__ wt3h,
    const float* __restrict__ fc1b, float* __restrict__ out) {
  const int n = blockIdx.x * 4 + (threadIdx.x >> 6);   // one wave per dst node
  const int lane = threadIdx.x & 63;
  const int q = lane >> 4, l16 = lane & 15;

  // B fragments (8 KB table, L1-resident)
  v8hf bfrag[8];
  {
    const _Float16* brow = wt3h + l16 * 256 + q * 8;
    #pragma unroll
    for (int kci = 0; kci < 8; ++kci)
      bfrag[kci] = *(const v8hf*)(brow + kci * 32);
  }
  // dst-row chunks (0.5 factor folded into wt3h)
  v8hf hdv[8];
  {
    const _Float16* drow = h + (size_t)n * 256 + q * 8;
    #pragma unroll
    for (int kci = 0; kci < 8; ++kci)
      hdv[kci] = *(const v8hf*)(drow + kci * 32);
  }
  const float bn = (l16 < 3) ? fc1b[l16] : 0.f;

  const int beg = offsets[n], end = offsets[n + 1];
  for (int c = beg; c < end; c += 16) {
    const int idx = c + l16;
    int s = -1, eid = -1;
    if (idx < end) { const int2 p = se[idx]; s = p.x; eid = p.y; }

    v8hf av[8] = {};
    if (s >= 0) {
      const _Float16* srow = h + (size_t)s * 256 + q * 8;
      #pragma unroll
      for (int kci = 0; kci < 8; ++kci)
        av[kci] = *(const v8hf*)(srow + kci * 32);
    }

    v4f acc = {0.f, 0.f, 0.f, 0.f};
    #pragma unroll
    for (int kci = 0; kci < 8; ++kci) {
      const v8hf ar = av[kci] * hdv[kci];     // v_pk_mul_f16 x4
      acc = __builtin_amdgcn_mfma_f32_16x16x32_f16(ar, bfrag[kci], acc, 0, 0, 0);
    }

    // lane (q, l16=score idx) holds edges m=q*4+r in acc[r]
    #pragma unroll
    for (int r = 0; r < 4; ++r) {
      const int m = q * 4 + r;
      const int em = __shfl(eid, m, 16);      // eid lives in lane l16==m of segment
      if (l16 < 3 && c + m < end && em >= 0)
        out[(size_t)em * 3 + l16] = acc[r] + bn;
    }
  }
}

// ---------------------------------------------------------------------------
static inline size_t align256(size_t b) { return (b + 255) & ~(size_t)255; }

extern "C" void kernel_launch(void* const* d_in, const int* in_sizes, int n_in,
                              void* d_out, int out_size, void* d_ws, size_t ws_size,
                              hipStream_t stream) {
  const float* x    = (const float*)d_in[0];
  const int*   ei   = (const int*)  d_in[1];   // [2,E] flat: [0:E]=src, [E:2E]=dst
  const float* W    = (const float*)d_in[2];
  const float* attS = (const float*)d_in[3];
  const float* attD = (const float*)d_in[4];
  const float* bias = (const float*)d_in[5];
  const float* fc1W = (const float*)d_in[6];
  const float* fc1b = (const float*)d_in[7];
  float*       out  = (float*)d_out;
  char*        ws   = (char*)d_ws;

  size_t off = 0;
  auto alloc = [&](size_t bytes) -> void* {
    void* p = ws + off;
    off += align256(bytes);
    return p;
  };
  _Float16* xh     = (_Float16*)alloc((size_t)N * F * sizeof(_Float16)); // 25.6 MB
  _Float16* wt     = (_Float16*)alloc((size_t)F * F * sizeof(_Float16)); // 128 KB
  _Float16* wt3h   = (_Float16*)alloc((size_t)16 * F * sizeof(_Float16)); // 8 KB
  __half*   xp     = (__half*)  alloc((size_t)N * F * sizeof(__half));   // 25.6 MB
  __half*   hbuf   = (__half*)  alloc((size_t)N * F * sizeof(__half));   // 25.6 MB
  float*    a_src  = (float*)   alloc((size_t)N * 4 * sizeof(float));
  float*    a_dst  = (float*)   alloc((size_t)N * 4 * sizeof(float));
  int*      counts = (int*)     alloc((size_t)N * sizeof(int));
  int*      offs   = (int*)     alloc((size_t)(N + 1) * sizeof(int));
  int*      partial= (int*)     alloc(256 * sizeof(int));
  int*      cursor = (int*)     alloc((size_t)N * sizeof(int));
  int2*     se     = (int2*)    alloc((size_t)EL * sizeof(int2));        // 13.2 MB

  hipMemsetAsync(counts, 0, (size_t)N * sizeof(int), stream);

  k_cvt_x<<<(N * F / 4 + 255) / 256, 256, 0, stream>>>(x, xh);
  k_cvt_w<<<F * F / 256, 256, 0, stream>>>(W, wt);
  k_cvt_w3<<<16, 256, 0, stream>>>(fc1W, wt3h);
  k_xw_mfma<<<N / 16, 256, 0, stream>>>(xh, wt, attS, attD, xp, a_src, a_dst);
  k_hist<<<(E + 255) / 256, 256, 0, stream>>>(ei, counts);
  k_scan1<<<NBLK, 256, 0, stream>>>(counts, offs, partial);
  k_scan2<<<1, 256, 0, stream>>>(partial);
  k_scan3<<<NBLK, 256, 0, stream>>>(offs, partial, cursor);
  k_scatter<<<(EL + 255) / 256, 256, 0, stream>>>(ei, cursor, se);
  k_agg<<<N / 2, 128, 0, stream>>>(xp, a_src, a_dst, se, offs, bias, hbuf);
  k_score_mfma<<<(N + 3) / 4, 256, 0, stream>>>((const _Float16*)hbuf, se, offs,
                                                wt3h, fc1b, out);
}

// Round 7
// 594.661 us; speedup vs baseline: 2.0602x; 1.1183x over previous
//
#include <hip/hip_runtime.h>
#include <hip/hip_fp16.h>
#include <math.h>

// Problem constants
constexpr int N    = 50000;
constexpr int E    = 1600000;
constexpr int F    = 256;        // HEADS*HID
constexpr int EL   = E + N;      // edges + self loops
constexpr int NBLK = (N + 255) / 256;  // 196 scan blocks
constexpr int CH   = (EL + 15) / 16;   // 16-edge score chunks

typedef _Float16 v8hf __attribute__((ext_vector_type(8)));
typedef float    v4f  __attribute__((ext_vector_type(4)));

// ---------------------------------------------------------------------------
// Prep: wt = W^T fp16; wt3h = (0.5*fc1W)^T fp16 padded to 16 cols; zero counts.
// One launch, 256 blocks x 256.
// ---------------------------------------------------------------------------
__global__ __launch_bounds__(256) void k_prep(
    const float* __restrict__ W, const float* __restrict__ fc1W,
    _Float16* __restrict__ wt, _Float16* __restrict__ wt3h,
    int* __restrict__ counts) {
  const int t = blockIdx.x * 256 + threadIdx.x;    // 65536 threads
  {
    const int n = t >> 8, k = t & 255;
    wt[t] = (_Float16)W[k * 256 + n];
  }
  if (t < 4096) {
    const int n = t >> 8, k = t & 255;
    wt3h[t] = (n < 3) ? (_Float16)(0.5f * fc1W[k * 3 + n]) : (_Float16)0.f;
  }
  if (t < N) counts[t] = 0;
}

// ---------------------------------------------------------------------------
// xp = x @ W via MFMA 16x16x32 f16 (fp32 accumulate), fp32 x converted inline.
// Block = 256 thr = 4 waves; wave w owns cols 64w..64w+63 (== head w) of a
// 16-row strip. Epilogue: xp fp16; a_src/a_dst from fp32 accumulators.
// Tail: grid-stride dst histogram (counts zeroed by k_prep, prior launch).
// ---------------------------------------------------------------------------
__global__ __launch_bounds__(256) void k_xw_mfma(
    const float* __restrict__ x, const _Float16* __restrict__ wt,
    const float* __restrict__ att_src, const float* __restrict__ att_dst,
    const int* __restrict__ ei, int* __restrict__ counts,
    __half* __restrict__ xp, float* __restrict__ a_src, float* __restrict__ a_dst) {
  const int wv   = threadIdx.x >> 6;
  const int lane = threadIdx.x & 63;
  const int q = lane >> 4, l16 = lane & 15;
  const int m0 = blockIdx.x * 16;
  const int c0 = wv * 64;

  v4f acc[4] = {{0,0,0,0},{0,0,0,0},{0,0,0,0},{0,0,0,0}};
  const float*    arow = x  + (size_t)(m0 + l16) * 256 + q * 8;
  const _Float16* brow = wt + (size_t)(c0 + l16) * 256 + q * 8;

  for (int kc = 0; kc < 256; kc += 32) {
    const float4 f0 = *(const float4*)(arow + kc);
    const float4 f1 = *(const float4*)(arow + kc + 4);
    const v8hf a = {(_Float16)f0.x, (_Float16)f0.y, (_Float16)f0.z, (_Float16)f0.w,
                    (_Float16)f1.x, (_Float16)f1.y, (_Float16)f1.z, (_Float16)f1.w};
    #pragma unroll
    for (int tn = 0; tn < 4; ++tn) {
      const v8hf b = *(const v8hf*)(brow + (size_t)tn * 16 * 256 + kc);
      acc[tn] = __builtin_amdgcn_mfma_f32_16x16x32_f16(a, b, acc[tn], 0, 0, 0);
    }
  }

  #pragma unroll
  for (int tn = 0; tn < 4; ++tn) {
    const int col = c0 + tn * 16 + l16;
    #pragma unroll
    for (int r = 0; r < 4; ++r)
      xp[(size_t)(m0 + q * 4 + r) * 256 + col] = __float2half_rn(acc[tn][r]);
  }

  float aw[4], dw[4];
  #pragma unroll
  for (int tn = 0; tn < 4; ++tn) {
    aw[tn] = att_src[c0 + tn * 16 + l16];
    dw[tn] = att_dst[c0 + tn * 16 + l16];
  }
  #pragma unroll
  for (int r = 0; r < 4; ++r) {
    float ps = acc[0][r]*aw[0] + acc[1][r]*aw[1] + acc[2][r]*aw[2] + acc[3][r]*aw[3];
    float pd = acc[0][r]*dw[0] + acc[1][r]*dw[1] + acc[2][r]*dw[2] + acc[3][r]*dw[3];
    #pragma unroll
    for (int off = 1; off < 16; off <<= 1) {
      ps += __shfl_xor(ps, off, 16);
      pd += __shfl_xor(pd, off, 16);
    }
    if (l16 == 0) {
      a_src[(m0 + q * 4 + r) * 4 + wv] = ps;
      a_dst[(m0 + q * 4 + r) * 4 + wv] = pd;
    }
  }

  // dst-degree histogram tail (grid = 3125*256 = 800000 threads)
  const int gid = blockIdx.x * 256 + threadIdx.x;
  for (int i = gid; i < E; i += 800000) atomicAdd(&counts[ei[E + i]], 1);
}

// ---------------------------------------------------------------------------
// CSR: scan1 (local exclusive + partials) -> scan3b (self-prefix of 196
// partials per block, add, write offsets+cursor) -> scatter.
// ---------------------------------------------------------------------------
__global__ __launch_bounds__(256) void k_scan1(
    const int* __restrict__ counts, int* __restrict__ offsets, int* __restrict__ partials) {
  __shared__ int s[256];
  const int t = threadIdx.x;
  const int i = blockIdx.x * 256 + t;
  const int v = (i < N) ? counts[i] + 1 : 0;     // +1 = self loop
  s[t] = v;
  __syncthreads();
  for (int off = 1; off < 256; off <<= 1) {
    const int add = (t >= off) ? s[t - off] : 0;
    __syncthreads();
    s[t] += add;
    __syncthreads();
  }
  if (i < N) offsets[i] = s[t] - v;              // local exclusive
  if (t == 255) partials[blockIdx.x] = s[255];   // block total
}

__global__ __launch_bounds__(256) void k_scan3b(
    int* __restrict__ offsets, const int* __restrict__ partials,
    int* __restrict__ cursor) {
  __shared__ int s[256];
  const int t = threadIdx.x, b = blockIdx.x;
  const int v = (t < NBLK) ? partials[t] : 0;
  s[t] = v;
  __syncthreads();
  for (int off = 1; off < 256; off <<= 1) {
    const int add = (t >= off) ? s[t - off] : 0;
    __syncthreads();
    s[t] += add;
    __syncthreads();
  }
  const int pre = (b == 0) ? 0 : s[b - 1];       // sum of partials[0..b-1]
  const int i = b * 256 + t;
  if (i < N) {
    const int val = offsets[i] + pre;
    offsets[i] = val;
    cursor[i]  = val;
  }
  if (i == 0) offsets[N] = EL;
}

// se[pos] = (src, eid, dst, 0); eid=-1 for self loops (no score output)
__global__ void k_scatter(const int* __restrict__ ei, int* __restrict__ cursor,
                          int4* __restrict__ se) {
  const int i = blockIdx.x * blockDim.x + threadIdx.x;
  if (i >= EL) return;
  int s, d, id;
  if (i < E) { s = ei[i]; d = ei[E + i]; id = i; }
  else       { s = d = i - E; id = -1; }
  const int pos = atomicAdd(&cursor[d], 1);
  se[pos] = make_int4(s, id, d, 0);
}

// ---------------------------------------------------------------------------
// Segment softmax + aggregation + bias + leaky. One block (2 waves) per node;
// waves split the 16-edge chunks (halves serial chain), LDS-combine at end.
// Lane owns features 4L..4L+3; weights computed by 16 lane-slots per head
// and broadcast via __shfl width 16. Gathers 8-deep in flight.
// ---------------------------------------------------------------------------
__global__ __launch_bounds__(128) void k_agg(
    const __half* __restrict__ xp, const float* __restrict__ a_src,
    const float* __restrict__ a_dst, const int4* __restrict__ se,
    const int* __restrict__ offsets, const float* __restrict__ bias,
    __half* __restrict__ h) {
  const int n = blockIdx.x;
  const int t = threadIdx.x;              // 0..127
  const int wv = t >> 6, lane = t & 63;
  const int hd = lane >> 4, es = lane & 15;
  const int beg = offsets[n], end = offsets[n + 1];
  const float adst = a_dst[n * 4 + hd];
  const __half* xb = xp + (size_t)lane * 4;

  float a0 = 0.f, a1 = 0.f, a2 = 0.f, a3 = 0.f, den = 0.f;

  for (int c = beg + wv * 16; c < end; c += 32) {
    const int cnt = min(16, end - c);
    int sv = 0; float wvv = 0.f;
    if (es < cnt) {
      sv = se[c + es].x;
      float al = a_src[sv * 4 + hd] + adst;
      al = al > 0.f ? al : 0.2f * al;
      wvv = __expf(al);
    }
    if (cnt == 16) {
      #pragma unroll
      for (int g = 0; g < 2; ++g) {
        int ss[8]; float ww[8]; uint2 rr[8];
        #pragma unroll
        for (int j = 0; j < 8; ++j) {
          ss[j] = __shfl(sv,  g * 8 + j, 16);
          ww[j] = __shfl(wvv, g * 8 + j, 16);
        }
        #pragma unroll
        for (int j = 0; j < 8; ++j) rr[j] = *(const uint2*)(xb + (size_t)ss[j] * 256);
        #pragma unroll
        for (int j = 0; j < 8; ++j) {
          const __half2* p = (const __half2*)&rr[j];
          const float2 lo = __half22float2(p[0]), hi = __half22float2(p[1]);
          den += ww[j];
          a0 += ww[j] * lo.x; a1 += ww[j] * lo.y;
          a2 += ww[j] * hi.x; a3 += ww[j] * hi.y;
        }
      }
    } else {
      for (int j = 0; j < cnt; ++j) {
        const int   s = __shfl(sv, j, 16);
        const float w = __shfl(wvv, j, 16);
        const uint2 r = *(const uint2*)(xb + (size_t)s * 256);
        const __half2* p = (const __half2*)&r;
        const float2 lo = __half22float2(p[0]), hi = __half22float2(p[1]);
        den += w;
        a0 += w * lo.x; a1 += w * lo.y; a2 += w * hi.x; a3 += w * hi.y;
      }
    }
  }

  __shared__ float ra[256];
  __shared__ float rd[64];
  if (wv == 1) {
    ra[lane * 4 + 0] = a0; ra[lane * 4 + 1] = a1;
    ra[lane * 4 + 2] = a2; ra[lane * 4 + 3] = a3;
    rd[lane] = den;
  }
  __syncthreads();
  if (wv == 0) {
    a0 += ra[lane * 4 + 0]; a1 += ra[lane * 4 + 1];
    a2 += ra[lane * 4 + 2]; a3 += ra[lane * 4 + 3];
    den += rd[lane];
    const float inv = 1.f / (den + 1e-16f);
    const float4 bv = *(const float4*)(bias + lane * 4);
    float o0 = a0 * inv + bv.x, o1 = a1 * inv + bv.y;
    float o2 = a2 * inv + bv.z, o3 = a3 * inv + bv.w;
    o0 = o0 > 0.f ? o0 : 0.01f * o0;
    o1 = o1 > 0.f ? o1 : 0.01f * o1;
    o2 = o2 > 0.f ? o2 : 0.01f * o2;
    o3 = o3 > 0.f ? o3 : 0.01f * o3;
    const __half2 p0 = __floats2half2_rn(o0, o1), p1 = __floats2half2_rn(o2, o3);
    uint2 st;
    st.x = *(const unsigned*)&p0;
    st.y = *(const unsigned*)&p1;
    *(uint2*)(h + (size_t)n * 256 + lane * 4) = st;
  }
}

// ---------------------------------------------------------------------------
// Edge scoring via MFMA over FLAT 16-edge chunks of the CSR array (uniform
// work, no per-node tail/imbalance). dst carried in se.z; dst-row loads are
// cache-hot (consecutive edges share dst). Per chunk a lane issues 17
// independent loads before compute. C: row=edge slot (q*4+r), col=score idx.
// ---------------------------------------------------------------------------
__global__ __launch_bounds__(256) void k_score_flat(
    const _Float16* __restrict__ h, const int4* __restrict__ se,
    const _Float16* __restrict__ wt3h, const float* __restrict__ fc1b,
    float* __restrict__ out, int total_waves) {
  const int lane = threadIdx.x & 63;
  const int q = lane >> 4, l16 = lane & 15;
  const int wgid = blockIdx.x * 4 + (threadIdx.x >> 6);

  v8hf bfrag[8];
  {
    const _Float16* brow = wt3h + l16 * 256 + q * 8;
    #pragma unroll
    for (int kci = 0; kci < 8; ++kci) bfrag[kci] = *(const v8hf*)(brow + kci * 32);
  }
  const float bn = (l16 < 3) ? fc1b[l16] : 0.f;

  for (int ch = wgid; ch < CH; ch += total_waves) {
    const int idx = ch * 16 + l16;
    int s = 0, d = 0, eid = -1;
    if (idx < EL) { const int4 p = se[idx]; s = p.x; eid = p.y; d = p.z; }

    const _Float16* srow = h + (size_t)s * 256 + q * 8;
    const _Float16* drow = h + (size_t)d * 256 + q * 8;
    v8hf av[8], dv[8];
    #pragma unroll
    for (int kci = 0; kci < 8; ++kci) av[kci] = *(const v8hf*)(srow + kci * 32);
    #pragma unroll
    for (int kci = 0; kci < 8; ++kci) dv[kci] = *(const v8hf*)(drow + kci * 32);

    v4f acc = {0.f, 0.f, 0.f, 0.f};
    #pragma unroll
    for (int kci = 0; kci < 8; ++kci) {
      const v8hf ar = av[kci] * dv[kci];     // v_pk_mul_f16 x4
      acc = __builtin_amdgcn_mfma_f32_16x16x32_f16(ar, bfrag[kci], acc, 0, 0, 0);
    }

    #pragma unroll
    for (int r = 0; r < 4; ++r) {
      const int m = q * 4 + r;
      const int em = __shfl(eid, m, 16);     // eid lives in lane l16==m of group
      if (l16 < 3 && em >= 0)
        out[(size_t)em * 3 + l16] = acc[r] + bn;
    }
  }
}

// ---------------------------------------------------------------------------
static inline size_t align256(size_t b) { return (b + 255) & ~(size_t)255; }

extern "C" void kernel_launch(void* const* d_in, const int* in_sizes, int n_in,
                              void* d_out, int out_size, void* d_ws, size_t ws_size,
                              hipStream_t stream) {
  const float* x    = (const float*)d_in[0];
  const int*   ei   = (const int*)  d_in[1];   // [2,E] flat: [0:E]=src, [E:2E]=dst
  const float* W    = (const float*)d_in[2];
  const float* attS = (const float*)d_in[3];
  const float* attD = (const float*)d_in[4];
  const float* bias = (const float*)d_in[5];
  const float* fc1W = (const float*)d_in[6];
  const float* fc1b = (const float*)d_in[7];
  float*       out  = (float*)d_out;
  char*        ws   = (char*)d_ws;

  size_t off = 0;
  auto alloc = [&](size_t bytes) -> void* {
    void* p = ws + off;
    off += align256(bytes);
    return p;
  };
  _Float16* wt     = (_Float16*)alloc((size_t)F * F * sizeof(_Float16));  // 128 KB
  _Float16* wt3h   = (_Float16*)alloc((size_t)16 * F * sizeof(_Float16)); // 8 KB
  __half*   xp     = (__half*)  alloc((size_t)N * F * sizeof(__half));    // 25.6 MB
  __half*   hbuf   = (__half*)  alloc((size_t)N * F * sizeof(__half));    // 25.6 MB
  float*    a_src  = (float*)   alloc((size_t)N * 4 * sizeof(float));
  float*    a_dst  = (float*)   alloc((size_t)N * 4 * sizeof(float));
  int*      counts = (int*)     alloc((size_t)N * sizeof(int));
  int*      offs   = (int*)     alloc((size_t)(N + 1) * sizeof(int));
  int*      partial= (int*)     alloc(256 * sizeof(int));
  int*      cursor = (int*)     alloc((size_t)N * sizeof(int));
  int4*     se     = (int4*)    alloc((size_t)EL * sizeof(int4));         // 26.4 MB

  k_prep<<<256, 256, 0, stream>>>(W, fc1W, wt, wt3h, counts);
  k_xw_mfma<<<N / 16, 256, 0, stream>>>(x, wt, attS, attD, ei, counts,
                                        xp, a_src, a_dst);
  k_scan1<<<NBLK, 256, 0, stream>>>(counts, offs, partial);
  k_scan3b<<<NBLK, 256, 0, stream>>>(offs, partial, cursor);
  k_scatter<<<(EL + 255) / 256, 256, 0, stream>>>(ei, cursor, se);
  k_agg<<<N, 128, 0, stream>>>(xp, a_src, a_dst, se, offs, bias, hbuf);
  const int score_blocks = 4096;
  k_score_flat<<<score_blocks, 256, 0, stream>>>((const _Float16*)hbuf, se, wt3h,
                                                 fc1b, out, score_blocks * 4);
}